// Round 2
// baseline (324.973 us; speedup 1.0000x reference)
//
#include <hip/hip_runtime.h>

typedef unsigned short u16;
typedef short bf16x8 __attribute__((ext_vector_type(8)));
typedef float f32x4 __attribute__((ext_vector_type(4)));

#define D_IN 2048
#define H_DIM 2048
#define K_CH 4096

__device__ __forceinline__ u16 f2bf(float f) {
  unsigned int u = __float_as_uint(f);
  u += 0x7fffu + ((u >> 16) & 1u);   // round-to-nearest-even
  return (u16)(u >> 16);
}
__device__ __forceinline__ float bf2f(unsigned int u) {
  return __uint_as_float(u << 16);
}
__device__ __forceinline__ float sigmoidf(float x) {
  return 1.0f / (1.0f + __expf(-x));
}

// ---------------------------------------------------------------------------
// Kernel A: h_sum[h] = sum_k children_h[k][h]  (fp32 in, fp32 partials via
// one atomicAdd per column per block) AND convert children_h -> bf16 copy.
// 256 blocks x 16 rows; thread t covers columns t*8..t*8+7.
// ---------------------------------------------------------------------------
__global__ __launch_bounds__(256) void khsum_cvt(const float* __restrict__ ch,
                                                 float* __restrict__ hsum,
                                                 u16* __restrict__ chb) {
  const int t = threadIdx.x;
  const int r0 = blockIdx.x * 16;
  float s0 = 0.f, s1 = 0.f, s2 = 0.f, s3 = 0.f, s4 = 0.f, s5 = 0.f, s6 = 0.f, s7 = 0.f;
  for (int r = 0; r < 16; ++r) {
    const float4* p = (const float4*)(ch + (size_t)(r0 + r) * H_DIM + t * 8);
    float4 a = p[0], b = p[1];
    s0 += a.x; s1 += a.y; s2 += a.z; s3 += a.w;
    s4 += b.x; s5 += b.y; s6 += b.z; s7 += b.w;
    uint4 w;
    w.x = (unsigned)f2bf(a.x) | ((unsigned)f2bf(a.y) << 16);
    w.y = (unsigned)f2bf(a.z) | ((unsigned)f2bf(a.w) << 16);
    w.z = (unsigned)f2bf(b.x) | ((unsigned)f2bf(b.y) << 16);
    w.w = (unsigned)f2bf(b.z) | ((unsigned)f2bf(b.w) << 16);
    *(uint4*)(chb + (size_t)(r0 + r) * H_DIM + t * 8) = w;
  }
  float* p = hsum + t * 8;
  atomicAdd(p + 0, s0); atomicAdd(p + 1, s1);
  atomicAdd(p + 2, s2); atomicAdd(p + 3, s3);
  atomicAdd(p + 4, s4); atomicAdd(p + 5, s5);
  atomicAdd(p + 6, s6); atomicAdd(p + 7, s7);
}

// ---------------------------------------------------------------------------
// Kernel B: convert W_fh (fp32, 4M elems) -> bf16. 8 elems/thread.
// ---------------------------------------------------------------------------
__global__ __launch_bounds__(256) void kcvt_w(const float* __restrict__ w,
                                              u16* __restrict__ wb) {
  const size_t i = ((size_t)blockIdx.x * 256 + threadIdx.x) * 8;
  const float4* p = (const float4*)(w + i);
  float4 a = p[0], b = p[1];
  uint4 o;
  o.x = (unsigned)f2bf(a.x) | ((unsigned)f2bf(a.y) << 16);
  o.y = (unsigned)f2bf(a.z) | ((unsigned)f2bf(a.w) << 16);
  o.z = (unsigned)f2bf(b.x) | ((unsigned)f2bf(b.y) << 16);
  o.w = (unsigned)f2bf(b.z) | ((unsigned)f2bf(b.w) << 16);
  *(uint4*)(wb + i) = o;
}

// ---------------------------------------------------------------------------
// Kernel C: one wave per output row, fp32.
//   rows 0..6143   : iou[row] = W_iou_x[row]@x + b_iou_x + W_iou_h[row]@h_sum + b_iou_h
//   rows 6144..8191: g[h] = W_fx[h]@x + b_fx[h] + b_fh[h]
// ---------------------------------------------------------------------------
__global__ __launch_bounds__(256) void kmatvec(
    const float* __restrict__ Wix, const float* __restrict__ bix,
    const float* __restrict__ Wih, const float* __restrict__ bih,
    const float* __restrict__ Wfx, const float* __restrict__ bfx,
    const float* __restrict__ bfh, const float* __restrict__ x,
    const float* __restrict__ hsum, float* __restrict__ iou,
    float* __restrict__ g) {
  const int wave = threadIdx.x >> 6, lane = threadIdx.x & 63;
  const int row = blockIdx.x * 4 + wave;  // 0..8191
  float s = 0.f;
  if (row < 6144) {
    const float4* wx = (const float4*)(Wix + (size_t)row * D_IN);
    const float4* wh = (const float4*)(Wih + (size_t)row * H_DIM);
    const float4* xv = (const float4*)x;
    const float4* hv = (const float4*)hsum;
#pragma unroll
    for (int i = 0; i < 8; ++i) {
      int idx = i * 64 + lane;
      float4 a = wx[idx], b = xv[idx];
      s += a.x * b.x + a.y * b.y + a.z * b.z + a.w * b.w;
      float4 c = wh[idx], d = hv[idx];
      s += c.x * d.x + c.y * d.y + c.z * d.z + c.w * d.w;
    }
#pragma unroll
    for (int off = 32; off > 0; off >>= 1) s += __shfl_xor(s, off);
    if (lane == 0) iou[row] = s + bix[row] + bih[row];
  } else {
    const int h = row - 6144;
    const float4* w = (const float4*)(Wfx + (size_t)h * D_IN);
    const float4* xv = (const float4*)x;
#pragma unroll
    for (int i = 0; i < 8; ++i) {
      int idx = i * 64 + lane;
      float4 a = w[idx], b = xv[idx];
      s += a.x * b.x + a.y * b.y + a.z * b.z + a.w * b.w;
    }
#pragma unroll
    for (int off = 32; off > 0; off >>= 1) s += __shfl_xor(s, off);
    if (lane == 0) g[h] = s + bfx[h] + bfh[h];
  }
}

// ---------------------------------------------------------------------------
// Kernel D: fused bf16 GEMM + sigmoid + weighted K-reduction.
//   fh[k,h] = chb[k,:] @ wfhb[h,:]   (A.B^T, row-major, inner=2048)
//   acc[h] += sum_k sigmoid(g[h] + fh[k,h]) * children_c[k,h]  (cc fp32)
// 128x128 tile, BK=32, 4 waves (2x2 of 64x64), 16B global_load_lds staging,
// 16x16x32 bf16 MFMA, 4x4 accumulators/wave.
// ---------------------------------------------------------------------------
#define BM 128
#define BN 128
#define BK 32

__global__ __launch_bounds__(256) void kgemm(
    const u16* __restrict__ chb, const float* __restrict__ cc,
    const u16* __restrict__ wfhb, const float* __restrict__ g,
    float* __restrict__ accv) {
  __shared__ u16 As[BM * BK];
  __shared__ u16 Bs[BN * BK];

  const int t = threadIdx.x;
  const int wave = t >> 6, lane = t & 63;
  const int lrow = lane & 15, lquad = lane >> 4;
  const int wm = wave >> 1, wn = wave & 1;
  const int row0 = blockIdx.x * BM;  // children tile base (32 tiles)
  const int col0 = blockIdx.y * BN;  // h tile base (16 tiles)

  f32x4 acc[4][4] = {};

  const int stage_row = t >> 2;      // 0..63
  const int stage_k = (t & 3) * 8;   // 0,8,16,24

  for (int kb = 0; kb < D_IN / BK; ++kb) {
    __syncthreads();
    const u16* ag = chb  + (size_t)(row0 + stage_row) * H_DIM + kb * BK + stage_k;
    const u16* bg = wfhb + (size_t)(col0 + stage_row) * H_DIM + kb * BK + stage_k;
    __builtin_amdgcn_global_load_lds(
        (const __attribute__((address_space(1))) void*)ag,
        (__attribute__((address_space(3))) void*)(As + wave * 512), 16, 0, 0);
    __builtin_amdgcn_global_load_lds(
        (const __attribute__((address_space(1))) void*)(ag + (size_t)64 * H_DIM),
        (__attribute__((address_space(3))) void*)(As + 2048 + wave * 512), 16, 0, 0);
    __builtin_amdgcn_global_load_lds(
        (const __attribute__((address_space(1))) void*)bg,
        (__attribute__((address_space(3))) void*)(Bs + wave * 512), 16, 0, 0);
    __builtin_amdgcn_global_load_lds(
        (const __attribute__((address_space(1))) void*)(bg + (size_t)64 * H_DIM),
        (__attribute__((address_space(3))) void*)(Bs + 2048 + wave * 512), 16, 0, 0);
    __syncthreads();

    bf16x8 fragA[4], fragB[4];
#pragma unroll
    for (int i = 0; i < 4; ++i)
      fragA[i] = *(const bf16x8*)(As + (wm * 64 + i * 16 + lrow) * BK + lquad * 8);
#pragma unroll
    for (int i = 0; i < 4; ++i)
      fragB[i] = *(const bf16x8*)(Bs + (wn * 64 + i * 16 + lrow) * BK + lquad * 8);
#pragma unroll
    for (int mi = 0; mi < 4; ++mi)
#pragma unroll
      for (int ni = 0; ni < 4; ++ni)
        acc[mi][ni] = __builtin_amdgcn_mfma_f32_16x16x32_bf16(
            fragA[mi], fragB[ni], acc[mi][ni], 0, 0, 0);
  }

  // Epilogue. C/D layout: col = lane&15, row = (lane>>4)*4 + reg.
#pragma unroll
  for (int ni = 0; ni < 4; ++ni) {
    const int colg = col0 + wn * 64 + ni * 16 + lrow;
    const float gv = g[colg];
    float s = 0.f;
#pragma unroll
    for (int mi = 0; mi < 4; ++mi) {
      const int rowg = row0 + wm * 64 + mi * 16 + lquad * 4;
#pragma unroll
      for (int r = 0; r < 4; ++r) {
        float f = sigmoidf(gv + acc[mi][ni][r]);
        s += f * cc[(size_t)(rowg + r) * H_DIM + colg];
      }
    }
    s += __shfl_xor(s, 16);
    s += __shfl_xor(s, 32);
    if (lquad == 0) atomicAdd(accv + colg, s);
  }
}

// ---------------------------------------------------------------------------
// Kernel E: finalize (fp32 out).  iou = [i|o|u]; c = sig(i)*tanh(u) + acc;
// h = sig(o)*tanh(c).  out = [sig(o) | c | h].
// ---------------------------------------------------------------------------
__global__ __launch_bounds__(256) void kfinal(const float* __restrict__ iou,
                                              const float* __restrict__ accv,
                                              float* __restrict__ out) {
  const int h = blockIdx.x * 256 + threadIdx.x;
  float si = sigmoidf(iou[h]);
  float so = sigmoidf(iou[H_DIM + h]);
  float tu = tanhf(iou[2 * H_DIM + h]);
  float c = si * tu + accv[h];
  float hh = so * tanhf(c);
  out[h] = so;
  out[H_DIM + h] = c;
  out[2 * H_DIM + h] = hh;
}

extern "C" void kernel_launch(void* const* d_in, const int* in_sizes, int n_in,
                              void* d_out, int out_size, void* d_ws, size_t ws_size,
                              hipStream_t stream) {
  const float* x   = (const float*)d_in[0];   // input [2048]
  const float* cc  = (const float*)d_in[1];   // children_c [4096,2048]
  const float* ch  = (const float*)d_in[2];   // children_h [4096,2048]
  const float* Wix = (const float*)d_in[3];   // W_iou_x [6144,2048]
  const float* bix = (const float*)d_in[4];   // b_iou_x [6144]
  const float* Wih = (const float*)d_in[5];   // W_iou_h [6144,2048]
  const float* bih = (const float*)d_in[6];   // b_iou_h [6144]
  const float* Wfx = (const float*)d_in[7];   // W_fx [2048,2048]
  const float* bfx = (const float*)d_in[8];   // b_fx [2048]
  const float* Wfh = (const float*)d_in[9];   // W_fh [2048,2048]
  const float* bfh = (const float*)d_in[10];  // b_fh [2048]

  float* ws   = (float*)d_ws;
  float* hsum = ws;            // [2048]
  float* iou  = ws + 2048;     // [6144]
  float* g    = ws + 8192;     // [2048]
  float* accv = ws + 10240;    // [2048]
  u16* chb  = (u16*)(ws + 12288);            // [4096*2048] bf16
  u16* wfhb = chb + (size_t)K_CH * H_DIM;    // [2048*2048] bf16
  float* out = (float*)d_out;

  hipMemsetAsync(d_ws, 0, 12288 * sizeof(float), stream);
  khsum_cvt<<<256, 256, 0, stream>>>(ch, hsum, chb);
  kcvt_w<<<2048, 256, 0, stream>>>(Wfh, wfhb);
  kmatvec<<<2048, 256, 0, stream>>>(Wix, bix, Wih, bih, Wfx, bfx, bfh, x, hsum, iou, g);
  kgemm<<<dim3(32, 16), 256, 0, stream>>>(chb, cc, wfhb, g, accv);
  kfinal<<<8, 256, 0, stream>>>(iou, accv, out);
}